// Round 3
// baseline (2244.124 us; speedup 1.0000x reference)
//
#include <hip/hip_runtime.h>

#define S_LEN 256
#define BATCH 256

typedef _Float16 f16;
typedef _Float16 f16x8 __attribute__((ext_vector_type(8)));
typedef _Float16 f16x4 __attribute__((ext_vector_type(4)));
typedef float f32x4 __attribute__((ext_vector_type(4)));

__device__ inline float sigf(float x) { return 1.f / (1.f + __expf(-x)); }
__device__ inline float tanhf2(float x) { return 2.f * sigf(2.f * x) - 1.f; }

// ---------------- weight f32 -> f16 conversion ----------------
// dst layout (f16 elems): wihf@0, whhf@65536, wihb@131072, whhb@196608,
// swih@262144, swhh@524288, wwih@786432, wwhh@1048576  (total 1310720)
__global__ void k_convert(const float* __restrict__ w3, const float* __restrict__ w4,
                          const float* __restrict__ w6, const float* __restrict__ w7,
                          const float* __restrict__ w9, const float* __restrict__ w10,
                          const float* __restrict__ w12, const float* __restrict__ w13,
                          f16* __restrict__ dst) {
  int i = blockIdx.x * blockDim.x + threadIdx.x;
  const int n = 1310720;
  for (; i < n; i += gridDim.x * blockDim.x) {
    float v;
    if (i < 262144) {
      int m = i >> 16, j = i & 65535;
      v = (m == 0 ? w3 : m == 1 ? w4 : m == 2 ? w6 : w7)[j];
    } else {
      int k = i - 262144;
      int m = k >> 18, j = k & 262143;
      v = (m == 0 ? w9 : m == 1 ? w10 : m == 2 ? w12 : w13)[j];
    }
    dst[i] = (f16)v;
  }
}

__global__ void k_zero(unsigned* __restrict__ p, int n) {
  int i = blockIdx.x * blockDim.x + threadIdx.x;
  for (; i < n; i += gridDim.x * blockDim.x) p[i] = 0u;
}

// ---------------- embedding gather -> Xf [t][b][128] f16 ----------------
__global__ void k_gather(const int* __restrict__ insts, const float* __restrict__ emb,
                         f16* __restrict__ Xf) {
  int gid = blockIdx.x * blockDim.x + threadIdx.x;  // 0..2097151
  int row = gid >> 5;                               // t*B + b
  int ch = gid & 31;
  int t = row >> 8, b = row & 255;
  int v = insts[b * S_LEN + t];
  const float* src = emb + (size_t)v * 128 + ch * 4;
  f16x4 d;
  d[0] = (f16)src[0]; d[1] = (f16)src[1]; d[2] = (f16)src[2]; d[3] = (f16)src[3];
  *(f16x4*)&Xf[(size_t)row * 128 + ch * 4] = d;
}

// ---------------- char BiLSTM: 32 blocks (16 fwd + 16 bwd), Bblk=16 ----------------
// Weights held in VGPRs, pinned vs rematerialization with per-iter asm.
__global__ __launch_bounds__(512, 2)
void k_char(const f16* __restrict__ wbuf, const f16* __restrict__ Xf,
            const float* __restrict__ bias_f, const float* __restrict__ bias_b,
            f16* __restrict__ chars) {
  const int bwd = blockIdx.x >> 4;
  const int m0 = (blockIdx.x & 15) * 16;
  const f16* Wih = wbuf + (bwd ? 131072 : 0);
  const f16* Whh = wbuf + (bwd ? 196608 : 65536);
  const float* bias = bwd ? bias_b : bias_f;

  const int tid = threadIdx.x;
  const int lane = tid & 63;
  const int wave = tid >> 6;
  const int gw = wave >> 1;        // gate 0..3
  const int u0 = (wave & 1) * 64;  // unit offset within gate
  const int l15 = lane & 15;
  const int kb = (lane >> 4) * 8;

  __shared__ f16 xs[2][16][136];
  __shared__ f16 hs[16][136];
  __shared__ float gex[16][520];

  f32x4 fih[4][4], fhh[4][4];
  float bv[4];
#pragma unroll
  for (int tt = 0; tt < 4; ++tt) {
    int col = gw * 128 + u0 + tt * 16 + l15;  // 0..511
    bv[tt] = bias[col];
#pragma unroll
    for (int ks = 0; ks < 4; ++ks) {
      fih[tt][ks] = *(const f32x4*)&Wih[col * 128 + ks * 32 + kb];
      fhh[tt][ks] = *(const f32x4*)&Whh[col * 128 + ks * 32 + kb];
    }
  }

  for (int i = tid; i < 16 * 136; i += 512) ((f16*)hs)[i] = (f16)0.f;
  {
    int mm = tid >> 5, cc = (tid & 31) * 4;
    int t_in = bwd ? (S_LEN - 1) : 0;
    *(f16x4*)&xs[0][mm][cc] =
        *(const f16x4*)&Xf[(size_t)t_in * BATCH * 128 + (m0 + mm) * 128 + cc];
  }
  float cst[4] = {0.f, 0.f, 0.f, 0.f};
  const int cm = tid >> 5;        // cell batch row
  const int cu = (tid & 31) * 4;  // cell unit base
  __syncthreads();

  for (int s = 0; s < S_LEN; ++s) {
    // pin weight frags in VGPRs (prevents per-iter reload from L2)
#pragma unroll
    for (int tt = 0; tt < 4; ++tt)
#pragma unroll
      for (int ks = 0; ks < 4; ++ks)
        asm volatile("" : "+v"(fih[tt][ks]), "+v"(fhh[tt][ks]));

    const int par = s & 1;
    f32x4 acc[4];
#pragma unroll
    for (int tt = 0; tt < 4; ++tt) { f32x4 a = {bv[tt], bv[tt], bv[tt], bv[tt]}; acc[tt] = a; }
#pragma unroll
    for (int ks = 0; ks < 4; ++ks) {
      f16x8 ax = *(const f16x8*)&xs[par][l15][ks * 32 + kb];
      f16x8 ah = *(const f16x8*)&hs[l15][ks * 32 + kb];
#pragma unroll
      for (int tt = 0; tt < 4; ++tt) {
        acc[tt] = __builtin_amdgcn_mfma_f32_16x16x32_f16(
            ax, __builtin_bit_cast(f16x8, fih[tt][ks]), acc[tt], 0, 0, 0);
        acc[tt] = __builtin_amdgcn_mfma_f32_16x16x32_f16(
            ah, __builtin_bit_cast(f16x8, fhh[tt][ks]), acc[tt], 0, 0, 0);
      }
    }
    // prefetch next x into regs (independent of recurrence)
    f16x4 xreg;
    const int sn = s + 1;
    if (sn < S_LEN) {
      int t_in = bwd ? (S_LEN - 1 - sn) : sn;
      xreg = *(const f16x4*)&Xf[(size_t)t_in * BATCH * 128 + (m0 + cm) * 128 + cu];
    }
#pragma unroll
    for (int tt = 0; tt < 4; ++tt) {
      int col = gw * 128 + u0 + tt * 16 + l15;
#pragma unroll
      for (int r = 0; r < 4; ++r) gex[(lane >> 4) * 4 + r][col] = acc[tt][r];
    }
    __syncthreads();
    // cell update: thread (cm, cu..cu+3)
    f16x4 hv;
#pragma unroll
    for (int qq = 0; qq < 4; ++qq) {
      int u = cu + qq;
      float gi = gex[cm][u], gf = gex[cm][128 + u], gg = gex[cm][256 + u], go = gex[cm][384 + u];
      float c = sigf(gf) * cst[qq] + sigf(gi) * tanhf2(gg);
      cst[qq] = c;
      hv[qq] = (f16)(sigf(go) * tanhf2(c));
    }
    {
      int t_in = bwd ? (S_LEN - 1 - s) : s;
      int cbase = bwd ? (128 + cu) : cu;
      *(f16x4*)&chars[(size_t)t_in * BATCH * 256 + (m0 + cm) * 256 + cbase] = hv;
      *(f16x4*)&hs[cm][cu] = hv;
      if (sn < S_LEN) *(f16x4*)&xs[par ^ 1][cm][cu] = xreg;
    }
    __syncthreads();
  }
}

// ---------------- sub + word LSTM ----------------
// 16 teams (batch slices of 16) x 8 blocks (32 hidden units each), 512 thr.
// blockIdx = q*16 + team  ->  all 8 team members on one XCD (blockIdx%8 == team%8).
// Cross-block exchange: epoch-tagged u32 words ((tag<<16)|f16bits) published with
// relaxed agent-scope (sc1, LLC-coherent) stores; consumers poll the DATA words
// directly until tag==i+1. No flags, no vmcnt-drain, no acquire/release.
// 2-slot parity is safe: slot for step i can only be overwritten at step i+2,
// which transitively requires every block to have consumed step i.
__global__ __launch_bounds__(512, 2)
void k_subword(const f16* __restrict__ wbuf, const f16* __restrict__ chars,
               const int* __restrict__ golds,
               const float* __restrict__ b_sub, const float* __restrict__ b_wrd,
               unsigned* __restrict__ h1pub, unsigned* __restrict__ whpub,
               f16* __restrict__ H2) {
  const int team = blockIdx.x & 15;
  const int q = blockIdx.x >> 4;     // 0..7
  const int m0 = team * 16;
  const int h0 = q * 32;
  const int tid = threadIdx.x, lane = tid & 63, wave = tid >> 6;
  const int l15 = lane & 15, kb = (lane >> 4) * 8;
  const int g = wave >> 1;           // gate 0..3
  const int us = wave & 1;           // unit subtile

  const f16* sWih = wbuf + 262144;
  const f16* sWhh = wbuf + 524288;
  const f16* wWih = wbuf + 786432;
  const f16* wWhh = wbuf + 1048576;

  __shared__ f16 xs_s[16][264];
  __shared__ f16 h1_s[16][264];
  __shared__ f16 wh_s[16][264];
  __shared__ float gexS[16][130];
  __shared__ float gexW[16][130];
  __shared__ unsigned char golds_s[16][256];

  // weight frags: rows g*256 + h0 + us*16 + l15 of each [1024,256] matrix
  f32x4 fsi[8], fsh[8], fwi[8], fwh[8];
  const int wr = g * 256 + h0 + us * 16 + l15;
#pragma unroll
  for (int ks = 0; ks < 8; ++ks) {
    fsi[ks] = *(const f32x4*)&sWih[wr * 256 + ks * 32 + kb];
    fsh[ks] = *(const f32x4*)&sWhh[wr * 256 + ks * 32 + kb];
    fwi[ks] = *(const f32x4*)&wWih[wr * 256 + ks * 32 + kb];
    fwh[ks] = *(const f32x4*)&wWhh[wr * 256 + ks * 32 + kb];
  }
  const float bS = b_sub[wr], bW = b_wrd[wr];

  for (int j = tid; j < 16 * 256; j += 512)
    golds_s[j >> 8][j & 255] = (unsigned char)golds[(m0 + (j >> 8)) * S_LEN + (j & 255)];
  for (int j = tid; j < 16 * 264; j += 512) {
    ((f16*)xs_s)[j] = (f16)0.f;
    ((f16*)h1_s)[j] = (f16)0.f;
    ((f16*)wh_s)[j] = (f16)0.f;
  }
  const int cb = tid >> 5, cu = tid & 31;   // cell: batch row, own-unit
  const int sr = tid >> 5;                  // staging row
  const int c0 = (tid & 31) * 8;            // staging col base (8 units)
  float c_sub = 0.f, c_wrd = 0.f, wh_reg = 0.f;
  __syncthreads();

  for (int i = 0; i <= S_LEN; ++i) {
    const bool doW = (i > 0), doS = (i < S_LEN);
    const int slotbase = ((i & 1) * 16 + team) << 12;

    // pin weight frags in VGPRs
#pragma unroll
    for (int ks = 0; ks < 8; ++ks)
      asm volatile("" : "+v"(fsi[ks]), "+v"(fsh[ks]), "+v"(fwi[ks]), "+v"(fwh[ks]));

    // chars[i] prefetch into regs (xs for sub(i+1)) — independent of cross-block data
    f16x8 chpre;
    if (doS)
      chpre = *(const f16x8*)&chars[(size_t)i * BATCH * 256 + (m0 + sr) * 256 + c0];

    f32x4 accW = {bW, bW, bW, bW};
    f32x4 accS = {bS, bS, bS, bS};
    if (doW) {
#pragma unroll
      for (int ks = 0; ks < 8; ++ks) {
        f16x8 a1 = *(const f16x8*)&h1_s[l15][ks * 32 + kb];
        f16x8 aw = *(const f16x8*)&wh_s[l15][ks * 32 + kb];
        accW = __builtin_amdgcn_mfma_f32_16x16x32_f16(
            a1, __builtin_bit_cast(f16x8, fwi[ks]), accW, 0, 0, 0);
        accW = __builtin_amdgcn_mfma_f32_16x16x32_f16(
            aw, __builtin_bit_cast(f16x8, fwh[ks]), accW, 0, 0, 0);
      }
    }
    if (doS) {
      const bool keep = (i > 0) && (golds_s[l15][i > 0 ? i - 1 : 0] == 0);
      f16x8 z8 = {};
#pragma unroll
      for (int ks = 0; ks < 8; ++ks) {
        f16x8 axv = *(const f16x8*)&xs_s[l15][ks * 32 + kb];
        f16x8 a1 = *(const f16x8*)&h1_s[l15][ks * 32 + kb];
        a1 = keep ? a1 : z8;  // per-row state reset (stack jump reads zeros)
        accS = __builtin_amdgcn_mfma_f32_16x16x32_f16(
            axv, __builtin_bit_cast(f16x8, fsi[ks]), accS, 0, 0, 0);
        accS = __builtin_amdgcn_mfma_f32_16x16x32_f16(
            a1, __builtin_bit_cast(f16x8, fsh[ks]), accS, 0, 0, 0);
      }
    }
#pragma unroll
    for (int r = 0; r < 4; ++r) {
      int row = (lane >> 4) * 4 + r;
      int colp = g * 32 + us * 16 + l15;
      if (doW) gexW[row][colp] = accW[r];
      if (doS) gexS[row][colp] = accS[r];
    }
    __syncthreads();  // B1: gates visible

    const int gprev = (i > 0) ? (int)golds_s[cb][i - 1] : 1;
    f16 h1v = (f16)0.f;
    if (doW) {  // word cell for t = i-1; advance iff golds[b][t] != 0
      float gi = gexW[cb][cu], gf = gexW[cb][32 + cu], gg = gexW[cb][64 + cu],
            go = gexW[cb][96 + cu];
      float c2 = sigf(gf) * c_wrd + sigf(gi) * tanhf2(gg);
      float h2 = sigf(go) * tanhf2(c2);
      bool adv = (gprev != 0);
      if (adv) { c_wrd = c2; wh_reg = h2; }
      H2[(size_t)(i - 1) * BATCH * 256 + (m0 + cb) * 256 + h0 + cu] = (f16)h2;
    }
    if (doS) {  // sub cell for t = i; reset iff i==0 or golds[b][i-1] != 0
      float gi = gexS[cb][cu], gf = gexS[cb][32 + cu], gg = gexS[cb][64 + cu],
            go = gexS[cb][96 + cu];
      float cp = (gprev == 0) ? c_sub : 0.f;
      float c1 = sigf(gf) * cp + sigf(gi) * tanhf2(gg);
      c_sub = c1;
      h1v = (f16)(sigf(go) * tanhf2(c1));
      // publish h1_i and wh_state_{i-1}, tagged i+1
      const unsigned tag = (unsigned)(i + 1) << 16;
      const int pidx = slotbase + cb * 256 + h0 + cu;
      __hip_atomic_store(&h1pub[pidx],
                         tag | (unsigned)__builtin_bit_cast(unsigned short, h1v),
                         __ATOMIC_RELAXED, __HIP_MEMORY_SCOPE_AGENT);
      __hip_atomic_store(&whpub[pidx],
                         tag | (unsigned)__builtin_bit_cast(unsigned short, (f16)wh_reg),
                         __ATOMIC_RELAXED, __HIP_MEMORY_SCOPE_AGENT);
    }

    if (doS) {
      asm volatile("" ::: "memory");  // publishes must issue before the poll
      const unsigned tgt = (unsigned)(i + 1);
      const int base = slotbase + sr * 256 + c0;
      unsigned hw[8], ww[8];
#pragma unroll
      for (int k = 0; k < 8; ++k) { hw[k] = 0u; ww[k] = 0u; }
      while (true) {
        bool ok = true;
#pragma unroll
        for (int k = 0; k < 8; ++k) {
          if ((hw[k] >> 16) != tgt) {
            hw[k] = __hip_atomic_load(&h1pub[base + k], __ATOMIC_RELAXED,
                                      __HIP_MEMORY_SCOPE_AGENT);
            ok &= ((hw[k] >> 16) == tgt);
          }
          if ((ww[k] >> 16) != tgt) {
            ww[k] = __hip_atomic_load(&whpub[base + k], __ATOMIC_RELAXED,
                                      __HIP_MEMORY_SCOPE_AGENT);
            ok &= ((ww[k] >> 16) == tgt);
          }
        }
        if (ok) break;
      }
      // unpack to f16 and stage LDS for next iter
      union { unsigned u[4]; f16x8 v; } uh, uw;
#pragma unroll
      for (int k2 = 0; k2 < 4; ++k2) {
        uh.u[k2] = (hw[2 * k2] & 0xffffu) | (hw[2 * k2 + 1] << 16);
        uw.u[k2] = (ww[2 * k2] & 0xffffu) | (ww[2 * k2 + 1] << 16);
      }
      *(f16x8*)&h1_s[sr][c0] = uh.v;
      *(f16x8*)&wh_s[sr][c0] = uw.v;
      *(f16x8*)&xs_s[sr][c0] = chpre;
      __syncthreads();  // B4: LDS staged for next iter
    }
  }
}

// ---------------- classifier: out[b][t][c] = [h2 ; chars] @ clsW.T + clsb ----------------
__global__ __launch_bounds__(256)
void k_cls(const f16* __restrict__ H2, const f16* __restrict__ chars,
           const float* __restrict__ clsW, const float* __restrict__ clsb,
           float* __restrict__ out) {
  const int w = (blockIdx.x << 2) | (threadIdx.x >> 6);  // row = t*B + b
  const int lane = threadIdx.x & 63;
  const int t = w >> 8, b = w & 255;
  const f16* h2p = H2 + (size_t)w * 256;
  const f16* chp = chars + (size_t)w * 256;
  float s0 = 0.f, s1 = 0.f;
  f16x4 hv = *(const f16x4*)&h2p[lane * 4];
  f16x4 cv = *(const f16x4*)&chp[lane * 4];
#pragma unroll
  for (int qq = 0; qq < 4; ++qq) {
    int u = lane * 4 + qq;
    s0 += (float)hv[qq] * clsW[u] + (float)cv[qq] * clsW[256 + u];
    s1 += (float)hv[qq] * clsW[512 + u] + (float)cv[qq] * clsW[768 + u];
  }
#pragma unroll
  for (int off = 32; off >= 1; off >>= 1) {
    s0 += __shfl_down(s0, off);
    s1 += __shfl_down(s1, off);
  }
  if (lane == 0) {
    out[((size_t)b * S_LEN + t) * 2 + 0] = s0 + clsb[0];
    out[((size_t)b * S_LEN + t) * 2 + 1] = s1 + clsb[1];
  }
}

extern "C" void kernel_launch(void* const* d_in, const int* in_sizes, int n_in,
                              void* d_out, int out_size, void* d_ws, size_t ws_size,
                              hipStream_t stream) {
  const int* insts = (const int*)d_in[0];
  const int* golds = (const int*)d_in[1];
  const float* emb = (const float*)d_in[2];
  const float* wihf = (const float*)d_in[3];
  const float* whhf = (const float*)d_in[4];
  const float* bf = (const float*)d_in[5];
  const float* wihb = (const float*)d_in[6];
  const float* whhb = (const float*)d_in[7];
  const float* bb = (const float*)d_in[8];
  const float* swih = (const float*)d_in[9];
  const float* swhh = (const float*)d_in[10];
  const float* sb = (const float*)d_in[11];
  const float* wwih = (const float*)d_in[12];
  const float* wwhh = (const float*)d_in[13];
  const float* wb = (const float*)d_in[14];
  const float* clsW = (const float*)d_in[15];
  const float* clsb = (const float*)d_in[16];
  float* out = (float*)d_out;

  // workspace layout (bytes)
  const size_t OFF_W = 0;                  // 2,621,440
  const size_t OFF_XF = 2621440;           // +16,777,216 (dead after k_char)
  const size_t OFF_PUBH1 = OFF_XF + 4194304;  // 524,288 (overlaid on Xf)
  const size_t OFF_PUBWH = OFF_PUBH1 + 524288;
  const size_t OFF_CHARS = 19398656;       // +33,554,432
  const size_t OFF_H2 = 52953088;          // +33,554,432
  const size_t TOTAL = 87048192;
  if (ws_size < TOTAL) return;

  char* ws = (char*)d_ws;
  f16* wbuf = (f16*)(ws + OFF_W);
  f16* Xf = (f16*)(ws + OFF_XF);
  f16* chars = (f16*)(ws + OFF_CHARS);
  f16* H2 = (f16*)(ws + OFF_H2);
  unsigned* h1pub = (unsigned*)(ws + OFF_PUBH1);
  unsigned* whpub = (unsigned*)(ws + OFF_PUBWH);

  hipLaunchKernelGGL(k_convert, dim3(1024), dim3(256), 0, stream, wihf, whhf, wihb, whhb,
                     swih, swhh, wwih, wwhh, wbuf);
  hipLaunchKernelGGL(k_gather, dim3(8192), dim3(256), 0, stream, insts, emb, Xf);
  hipLaunchKernelGGL(k_char, dim3(32), dim3(512), 0, stream, wbuf, Xf, bf, bb, chars);
  // zero the epoch-tag pub region (inside Xf, so must run after k_char)
  hipLaunchKernelGGL(k_zero, dim3(512), dim3(256), 0, stream, (unsigned*)(ws + OFF_PUBH1),
                     262144);
  hipLaunchKernelGGL(k_subword, dim3(128), dim3(512), 0, stream, wbuf, chars, golds, sb, wb,
                     h1pub, whpub, H2);
  hipLaunchKernelGGL(k_cls, dim3(16384), dim3(256), 0, stream, H2, chars, clsW, clsb, out);
}

// Round 4
// 1359.396 us; speedup vs baseline: 1.6508x; 1.6508x over previous
//
#include <hip/hip_runtime.h>

#define S_LEN 256
#define BATCH 256

typedef _Float16 f16;
typedef _Float16 f16x8 __attribute__((ext_vector_type(8)));
typedef _Float16 f16x4 __attribute__((ext_vector_type(4)));
typedef float f32x4 __attribute__((ext_vector_type(4)));

__device__ inline float sigf(float x) { return 1.f / (1.f + __expf(-x)); }
__device__ inline float tanhf2(float x) { return 2.f * sigf(2.f * x) - 1.f; }

// ---------------- weight f32 -> f16 conversion ----------------
// dst layout (f16 elems): wihf@0, whhf@65536, wihb@131072, whhb@196608,
// swih@262144, swhh@524288, wwih@786432, wwhh@1048576  (total 1310720)
__global__ void k_convert(const float* __restrict__ w3, const float* __restrict__ w4,
                          const float* __restrict__ w6, const float* __restrict__ w7,
                          const float* __restrict__ w9, const float* __restrict__ w10,
                          const float* __restrict__ w12, const float* __restrict__ w13,
                          f16* __restrict__ dst) {
  int i = blockIdx.x * blockDim.x + threadIdx.x;
  const int n = 1310720;
  for (; i < n; i += gridDim.x * blockDim.x) {
    float v;
    if (i < 262144) {
      int m = i >> 16, j = i & 65535;
      v = (m == 0 ? w3 : m == 1 ? w4 : m == 2 ? w6 : w7)[j];
    } else {
      int k = i - 262144;
      int m = k >> 18, j = k & 262143;
      v = (m == 0 ? w9 : m == 1 ? w10 : m == 2 ? w12 : w13)[j];
    }
    dst[i] = (f16)v;
  }
}

__global__ void k_zero(unsigned* __restrict__ p, int n) {
  int i = blockIdx.x * blockDim.x + threadIdx.x;
  for (; i < n; i += gridDim.x * blockDim.x) p[i] = 0u;
}

// ---------------- embedding gather -> Xf [t][b][128] f16 ----------------
__global__ void k_gather(const int* __restrict__ insts, const float* __restrict__ emb,
                         f16* __restrict__ Xf) {
  int gid = blockIdx.x * blockDim.x + threadIdx.x;  // 0..2097151
  int row = gid >> 5;                               // t*B + b
  int ch = gid & 31;
  int t = row >> 8, b = row & 255;
  int v = insts[b * S_LEN + t];
  const float* src = emb + (size_t)v * 128 + ch * 4;
  f16x4 d;
  d[0] = (f16)src[0]; d[1] = (f16)src[1]; d[2] = (f16)src[2]; d[3] = (f16)src[3];
  *(f16x4*)&Xf[(size_t)row * 128 + ch * 4] = d;
}

// ---------------- char BiLSTM: 32 blocks (16 fwd + 16 bwd), Bblk=16 ----------------
// Weights loaded ONCE via volatile f32x4 (volatile loads cannot be
// rematerialized -> values stay pinned in VGPRs across the 256-step loop).
__global__ __launch_bounds__(512, 2)
void k_char(const f16* __restrict__ wbuf, const f16* __restrict__ Xf,
            const float* __restrict__ bias_f, const float* __restrict__ bias_b,
            f16* __restrict__ chars) {
  const int bwd = blockIdx.x >> 4;
  const int m0 = (blockIdx.x & 15) * 16;
  const f16* Wih = wbuf + (bwd ? 131072 : 0);
  const f16* Whh = wbuf + (bwd ? 196608 : 65536);
  const float* bias = bwd ? bias_b : bias_f;

  const int tid = threadIdx.x;
  const int lane = tid & 63;
  const int wave = tid >> 6;
  const int gw = wave >> 1;        // gate 0..3
  const int u0 = (wave & 1) * 64;  // unit offset within gate
  const int l15 = lane & 15;
  const int kb = (lane >> 4) * 8;

  __shared__ f16 xs[2][16][136];
  __shared__ f16 hs[16][136];
  __shared__ float gex[16][520];

  f32x4 fih[4][4], fhh[4][4];
  float bv[4];
#pragma unroll
  for (int tt = 0; tt < 4; ++tt) {
    int col = gw * 128 + u0 + tt * 16 + l15;  // 0..511
    bv[tt] = bias[col];
#pragma unroll
    for (int ks = 0; ks < 4; ++ks) {
      fih[tt][ks] = *(const volatile f32x4*)&Wih[col * 128 + ks * 32 + kb];
      fhh[tt][ks] = *(const volatile f32x4*)&Whh[col * 128 + ks * 32 + kb];
    }
  }

  for (int i = tid; i < 16 * 136; i += 512) ((f16*)hs)[i] = (f16)0.f;
  {
    int mm = tid >> 5, cc = (tid & 31) * 4;
    int t_in = bwd ? (S_LEN - 1) : 0;
    *(f16x4*)&xs[0][mm][cc] =
        *(const f16x4*)&Xf[(size_t)t_in * BATCH * 128 + (m0 + mm) * 128 + cc];
  }
  float cst[4] = {0.f, 0.f, 0.f, 0.f};
  const int cm = tid >> 5;        // cell batch row
  const int cu = (tid & 31) * 4;  // cell unit base
  __syncthreads();

  for (int s = 0; s < S_LEN; ++s) {
    const int par = s & 1;
    f32x4 acc[4];
#pragma unroll
    for (int tt = 0; tt < 4; ++tt) { f32x4 a = {bv[tt], bv[tt], bv[tt], bv[tt]}; acc[tt] = a; }
#pragma unroll
    for (int ks = 0; ks < 4; ++ks) {
      f16x8 ax = *(const f16x8*)&xs[par][l15][ks * 32 + kb];
      f16x8 ah = *(const f16x8*)&hs[l15][ks * 32 + kb];
#pragma unroll
      for (int tt = 0; tt < 4; ++tt) {
        acc[tt] = __builtin_amdgcn_mfma_f32_16x16x32_f16(
            ax, __builtin_bit_cast(f16x8, fih[tt][ks]), acc[tt], 0, 0, 0);
        acc[tt] = __builtin_amdgcn_mfma_f32_16x16x32_f16(
            ah, __builtin_bit_cast(f16x8, fhh[tt][ks]), acc[tt], 0, 0, 0);
      }
    }
    // prefetch next x into regs (independent of recurrence)
    f16x4 xreg;
    const int sn = s + 1;
    if (sn < S_LEN) {
      int t_in = bwd ? (S_LEN - 1 - sn) : sn;
      xreg = *(const f16x4*)&Xf[(size_t)t_in * BATCH * 128 + (m0 + cm) * 128 + cu];
    }
#pragma unroll
    for (int tt = 0; tt < 4; ++tt) {
      int col = gw * 128 + u0 + tt * 16 + l15;
#pragma unroll
      for (int r = 0; r < 4; ++r) gex[(lane >> 4) * 4 + r][col] = acc[tt][r];
    }
    __syncthreads();
    // cell update: thread (cm, cu..cu+3)
    f16x4 hv;
#pragma unroll
    for (int qq = 0; qq < 4; ++qq) {
      int u = cu + qq;
      float gi = gex[cm][u], gf = gex[cm][128 + u], gg = gex[cm][256 + u], go = gex[cm][384 + u];
      float c = sigf(gf) * cst[qq] + sigf(gi) * tanhf2(gg);
      cst[qq] = c;
      hv[qq] = (f16)(sigf(go) * tanhf2(c));
    }
    {
      int t_in = bwd ? (S_LEN - 1 - s) : s;
      int cbase = bwd ? (128 + cu) : cu;
      *(f16x4*)&chars[(size_t)t_in * BATCH * 256 + (m0 + cm) * 256 + cbase] = hv;
      *(f16x4*)&hs[cm][cu] = hv;
      if (sn < S_LEN) *(f16x4*)&xs[par ^ 1][cm][cu] = xreg;
    }
    __syncthreads();
  }
}

// ---------------- sub + word LSTM, stack semantics de-sugared ----------------
// R2 structure (proven 837us): 16 teams x 16 blocks x 256 thr, flag barrier,
// relaxed sc1 atomics. This round: weights pinned in VGPRs via volatile loads.
__global__ __launch_bounds__(256, 1)
void k_subword(const f16* __restrict__ wbuf, const f16* __restrict__ chars,
               const int* __restrict__ golds,
               const float* __restrict__ b_sub, const float* __restrict__ b_wrd,
               f16* __restrict__ h1buf, f16* __restrict__ whbuf,
               unsigned* __restrict__ flags, f16* __restrict__ H2) {
  const int team = blockIdx.x >> 4;
  const int q = blockIdx.x & 15;
  const int m0 = team * 16;
  const int h0 = q * 16;
  const int tid = threadIdx.x, lane = tid & 63, wave = tid >> 6;
  const int l15 = lane & 15, kb = (lane >> 4) * 8;

  const f16* sWih = wbuf + 262144;
  const f16* sWhh = wbuf + 524288;
  const f16* wWih = wbuf + 786432;
  const f16* wWhh = wbuf + 1048576;

  __shared__ f16 xs_s[16][264];
  __shared__ f16 h1_s[16][264];
  __shared__ f16 wh_s[16][264];
  __shared__ float gexS[16][68];
  __shared__ float gexW[16][68];
  __shared__ int golds_s[16][256];

  // weight fragments pinned in VGPRs: volatile loads are not rematerializable
  f32x4 fsi[8], fsh[8], fwi[8], fwh[8];
  const int wr = wave * 256 + h0 + l15;
#pragma unroll
  for (int ks = 0; ks < 8; ++ks) {
    fsi[ks] = *(const volatile f32x4*)&sWih[wr * 256 + ks * 32 + kb];
    fsh[ks] = *(const volatile f32x4*)&sWhh[wr * 256 + ks * 32 + kb];
    fwi[ks] = *(const volatile f32x4*)&wWih[wr * 256 + ks * 32 + kb];
    fwh[ks] = *(const volatile f32x4*)&wWhh[wr * 256 + ks * 32 + kb];
  }
  const float bS = b_sub[wr], bW = b_wrd[wr];

  for (int i = tid; i < 16 * 256; i += 256)
    golds_s[i >> 8][i & 255] = golds[(m0 + (i >> 8)) * S_LEN + (i & 255)];
  for (int i = tid; i < 16 * 264; i += 256) {
    ((f16*)xs_s)[i] = (f16)0.f;
    ((f16*)h1_s)[i] = (f16)0.f;
    ((f16*)wh_s)[i] = (f16)0.f;
  }
  const int cm = tid >> 4, cj = tid & 15;
  const int sr = tid >> 4;            // staging row
  const int sc = (tid & 15) * 16;     // staging col base (16 f16 = 32B per thread)
  float c_sub = 0.f, c_wrd = 0.f;
  __syncthreads();

  for (int i = 0; i <= S_LEN; ++i) {
    const bool doW = (i > 0), doS = (i < S_LEN);

    // chars[i] prefetch into regs — independent of the team flag, issue first
    f16x4 chpre[4];
    if (doS) {
#pragma unroll
      for (int p = 0; p < 4; ++p)
        chpre[p] = *(const f16x4*)&chars[(size_t)i * BATCH * 256 + (m0 + sr) * 256 + sc + p * 4];
    }

    f32x4 accW = {bW, bW, bW, bW};
    f32x4 accS = {bS, bS, bS, bS};
    if (doW) {
#pragma unroll
      for (int ks = 0; ks < 8; ++ks) {
        f16x8 a1 = *(const f16x8*)&h1_s[l15][ks * 32 + kb];
        f16x8 aw = *(const f16x8*)&wh_s[l15][ks * 32 + kb];
        accW = __builtin_amdgcn_mfma_f32_16x16x32_f16(
            a1, __builtin_bit_cast(f16x8, fwi[ks]), accW, 0, 0, 0);
        accW = __builtin_amdgcn_mfma_f32_16x16x32_f16(
            aw, __builtin_bit_cast(f16x8, fwh[ks]), accW, 0, 0, 0);
      }
    }
    if (doS) {
      const bool keep = (i > 0) && (golds_s[l15][i > 0 ? i - 1 : 0] == 0);
      f16x8 z8 = {};
#pragma unroll
      for (int ks = 0; ks < 8; ++ks) {
        f16x8 axv = *(const f16x8*)&xs_s[l15][ks * 32 + kb];
        f16x8 a1 = *(const f16x8*)&h1_s[l15][ks * 32 + kb];
        a1 = keep ? a1 : z8;  // per-row state reset (stack jump reads zeros)
        accS = __builtin_amdgcn_mfma_f32_16x16x32_f16(
            axv, __builtin_bit_cast(f16x8, fsi[ks]), accS, 0, 0, 0);
        accS = __builtin_amdgcn_mfma_f32_16x16x32_f16(
            a1, __builtin_bit_cast(f16x8, fsh[ks]), accS, 0, 0, 0);
      }
    }
#pragma unroll
    for (int r = 0; r < 4; ++r) {
      if (doW) gexW[(lane >> 4) * 4 + r][wave * 16 + l15] = accW[r];
      if (doS) gexS[(lane >> 4) * 4 + r][wave * 16 + l15] = accS[r];
    }
    __syncthreads();  // B1: gates visible

    const int gprev = (i > 0) ? golds_s[cm][i - 1] : 1;
    if (doW) {  // word cell for t = i-1; advance iff golds[b][t] != 0
      float gi = gexW[cm][cj], gf = gexW[cm][16 + cj], gg = gexW[cm][32 + cj],
            go = gexW[cm][48 + cj];
      float c2 = sigf(gf) * c_wrd + sigf(gi) * tanhf2(gg);
      float h2 = sigf(go) * tanhf2(c2);
      bool adv = (gprev != 0);
      if (adv) c_wrd = c2;
      float whold = (float)wh_s[cm][h0 + cj];
      f16 whnew = (f16)(adv ? h2 : whold);
      H2[(size_t)(i - 1) * BATCH * 256 + (m0 + cm) * 256 + h0 + cj] = (f16)h2;
      if (doS)
        __hip_atomic_store(
            (unsigned short*)&whbuf[(size_t)(i & 1) * 65536 + (m0 + cm) * 256 + h0 + cj],
            __builtin_bit_cast(unsigned short, whnew), __ATOMIC_RELAXED,
            __HIP_MEMORY_SCOPE_AGENT);
    }
    if (doS) {  // sub cell for t = i; reset iff i==0 or golds[b][i-1] != 0
      float gi = gexS[cm][cj], gf = gexS[cm][16 + cj], gg = gexS[cm][32 + cj],
            go = gexS[cm][48 + cj];
      float cp = (gprev == 0) ? c_sub : 0.f;
      float c1 = sigf(gf) * cp + sigf(gi) * tanhf2(gg);
      c_sub = c1;
      f16 h1 = (f16)(sigf(go) * tanhf2(c1));
      __hip_atomic_store(
          (unsigned short*)&h1buf[(size_t)(i & 1) * 65536 + (m0 + cm) * 256 + h0 + cj],
          __builtin_bit_cast(unsigned short, h1), __ATOMIC_RELAXED, __HIP_MEMORY_SCOPE_AGENT);
    }
    __syncthreads();  // B2: waitcnt vmcnt(0) — all sc1 publish stores acked at LLC

    if (doS) {
      if (tid == 0)
        __hip_atomic_store(&flags[(team * 16 + q) * 16], (unsigned)(i + 1), __ATOMIC_RELAXED,
                           __HIP_MEMORY_SCOPE_AGENT);
      if (tid < 64) {
        const unsigned tgt = (unsigned)(i + 1);
        while (true) {
          unsigned v = tgt;
          if (lane < 16)
            v = __hip_atomic_load(&flags[(team * 16 + lane) * 16], __ATOMIC_RELAXED,
                                  __HIP_MEMORY_SCOPE_AGENT);
          if (__all(v >= tgt)) break;
          __builtin_amdgcn_s_sleep(1);
        }
      }
      asm volatile("" ::: "memory");  // pin staging loads below the spin
      __syncthreads();  // B3: team barrier passed
      // stage h1_i, Wh_i from LLC; xs for sub(i+1) from prefetched regs
#pragma unroll
      for (int p = 0; p < 4; ++p) {
        int c4 = sc + p * 4;
        unsigned long long v1 = __hip_atomic_load(
            (const unsigned long long*)&h1buf[(size_t)(i & 1) * 65536 + (m0 + sr) * 256 + c4],
            __ATOMIC_RELAXED, __HIP_MEMORY_SCOPE_AGENT);
        unsigned long long v2 = __hip_atomic_load(
            (const unsigned long long*)&whbuf[(size_t)(i & 1) * 65536 + (m0 + sr) * 256 + c4],
            __ATOMIC_RELAXED, __HIP_MEMORY_SCOPE_AGENT);
        *(f16x4*)&h1_s[sr][c4] = __builtin_bit_cast(f16x4, v1);
        *(f16x4*)&wh_s[sr][c4] = __builtin_bit_cast(f16x4, v2);
        *(f16x4*)&xs_s[sr][c4] = chpre[p];
      }
      __syncthreads();  // B4: LDS staged for next iter
    }
  }
}

// ---------------- classifier: out[b][t][c] = [h2 ; chars] @ clsW.T + clsb ----------------
__global__ __launch_bounds__(256)
void k_cls(const f16* __restrict__ H2, const f16* __restrict__ chars,
           const float* __restrict__ clsW, const float* __restrict__ clsb,
           float* __restrict__ out) {
  const int w = (blockIdx.x << 2) | (threadIdx.x >> 6);  // row = t*B + b
  const int lane = threadIdx.x & 63;
  const int t = w >> 8, b = w & 255;
  const f16* h2p = H2 + (size_t)w * 256;
  const f16* chp = chars + (size_t)w * 256;
  float s0 = 0.f, s1 = 0.f;
  f16x4 hv = *(const f16x4*)&h2p[lane * 4];
  f16x4 cv = *(const f16x4*)&chp[lane * 4];
#pragma unroll
  for (int qq = 0; qq < 4; ++qq) {
    int u = lane * 4 + qq;
    s0 += (float)hv[qq] * clsW[u] + (float)cv[qq] * clsW[256 + u];
    s1 += (float)hv[qq] * clsW[512 + u] + (float)cv[qq] * clsW[768 + u];
  }
#pragma unroll
  for (int off = 32; off >= 1; off >>= 1) {
    s0 += __shfl_down(s0, off);
    s1 += __shfl_down(s1, off);
  }
  if (lane == 0) {
    out[((size_t)b * S_LEN + t) * 2 + 0] = s0 + clsb[0];
    out[((size_t)b * S_LEN + t) * 2 + 1] = s1 + clsb[1];
  }
}

extern "C" void kernel_launch(void* const* d_in, const int* in_sizes, int n_in,
                              void* d_out, int out_size, void* d_ws, size_t ws_size,
                              hipStream_t stream) {
  const int* insts = (const int*)d_in[0];
  const int* golds = (const int*)d_in[1];
  const float* emb = (const float*)d_in[2];
  const float* wihf = (const float*)d_in[3];
  const float* whhf = (const float*)d_in[4];
  const float* bf = (const float*)d_in[5];
  const float* wihb = (const float*)d_in[6];
  const float* whhb = (const float*)d_in[7];
  const float* bb = (const float*)d_in[8];
  const float* swih = (const float*)d_in[9];
  const float* swhh = (const float*)d_in[10];
  const float* sb = (const float*)d_in[11];
  const float* wwih = (const float*)d_in[12];
  const float* wwhh = (const float*)d_in[13];
  const float* wb = (const float*)d_in[14];
  const float* clsW = (const float*)d_in[15];
  const float* clsb = (const float*)d_in[16];
  float* out = (float*)d_out;

  // workspace layout (bytes)
  const size_t OFF_W = 0;                  // 2,621,440
  const size_t OFF_XF = 2621440;           // +16,777,216
  const size_t OFF_CHARS = 19398656;       // +33,554,432
  const size_t OFF_H2 = 52953088;          // +33,554,432
  const size_t OFF_H1 = 86507520;          // +262,144
  const size_t OFF_WH = 86769664;          // +262,144
  const size_t OFF_FLAGS = 87031808;       // +16,384
  const size_t TOTAL = 87048192;
  if (ws_size < TOTAL) return;

  char* ws = (char*)d_ws;
  f16* wbuf = (f16*)(ws + OFF_W);
  f16* Xf = (f16*)(ws + OFF_XF);
  f16* chars = (f16*)(ws + OFF_CHARS);
  f16* H2 = (f16*)(ws + OFF_H2);
  f16* h1buf = (f16*)(ws + OFF_H1);
  f16* whbuf = (f16*)(ws + OFF_WH);
  unsigned* flags = (unsigned*)(ws + OFF_FLAGS);

  hipLaunchKernelGGL(k_convert, dim3(1024), dim3(256), 0, stream, wihf, whhf, wihb, whhb,
                     swih, swhh, wwih, wwhh, wbuf);
  hipLaunchKernelGGL(k_zero, dim3(256), dim3(256), 0, stream, (unsigned*)(ws + OFF_H1),
                     135168);
  hipLaunchKernelGGL(k_gather, dim3(8192), dim3(256), 0, stream, insts, emb, Xf);
  hipLaunchKernelGGL(k_char, dim3(32), dim3(512), 0, stream, wbuf, Xf, bf, bb, chars);
  hipLaunchKernelGGL(k_subword, dim3(256), dim3(256), 0, stream, wbuf, chars, golds, sb, wb,
                     h1buf, whbuf, flags, H2);
  hipLaunchKernelGGL(k_cls, dim3(16384), dim3(256), 0, stream, H2, chars, clsW, clsb, out);
}